// Round 1
// 1619.918 us; speedup vs baseline: 1.7269x; 1.7269x over previous
//
#include <hip/hip_runtime.h>
#include <hip/hip_bf16.h>
#include <math.h>

// Problem constants
#define BB   2
#define LL   1024
#define DD   768
#define DIN  1536      // d_inner
#define NS   16        // d_state
#define DCV  4         // d_conv
#define DTRK 48        // dt_rank
#define NLAY 4
#define VV   32000
#define ROWS (BB*LL)   // 2048

// chunked scan
#define NCH  32        // number of chunks over L
#define CLEN (LL/NCH)  // 32 steps per chunk

typedef __attribute__((ext_vector_type(8))) short short8;
typedef __attribute__((ext_vector_type(4))) float f32x4;

// ---------------- elementwise / small kernels ----------------

__global__ __launch_bounds__(256) void embed_kernel(
    const int* __restrict__ tok, const float* __restrict__ emb,
    float* __restrict__ x) {
  int idx = blockIdx.x * 256 + threadIdx.x;          // 2048*768 total
  int row = idx / DD, c = idx - row * DD;
  x[idx] = emb[(size_t)tok[row] * DD + c];
}

// fp32 -> bf16, 4 elements/thread (n divisible by 4)
__global__ __launch_bounds__(256) void cvt_bf16_kernel(
    const float* __restrict__ in, __hip_bfloat16* __restrict__ out, int n4) {
  int i = blockIdx.x * 256 + threadIdx.x;
  if (i >= n4) return;
  float4 v = ((const float4*)in)[i];
  __hip_bfloat16 t0 = __float2bfloat16(v.x);
  __hip_bfloat16 t1 = __float2bfloat16(v.y);
  __hip_bfloat16 t2 = __float2bfloat16(v.z);
  __hip_bfloat16 t3 = __float2bfloat16(v.w);
  ushort4 pack = make_ushort4(*(unsigned short*)&t0, *(unsigned short*)&t1,
                              *(unsigned short*)&t2, *(unsigned short*)&t3);
  ((ushort4*)out)[i] = pack;
}

__global__ __launch_bounds__(256) void rmsnorm_kernel(
    const float* __restrict__ x, const float* __restrict__ w,
    __hip_bfloat16* __restrict__ xn) {
  int row = blockIdx.x;
  int t = threadIdx.x;
  const float* xr = x + (size_t)row * DD;
  float v0 = xr[t], v1 = xr[t + 256], v2 = xr[t + 512];
  float ss = v0 * v0 + v1 * v1 + v2 * v2;
#pragma unroll
  for (int off = 32; off > 0; off >>= 1) ss += __shfl_down(ss, off);
  __shared__ float sred[4];
  if ((t & 63) == 0) sred[t >> 6] = ss;
  __syncthreads();
  float tot = sred[0] + sred[1] + sred[2] + sred[3];
  float scale = rsqrtf(tot * (1.0f / DD) + 1e-5f);
  __hip_bfloat16* xo = xn + (size_t)row * DD;
  xo[t]       = __float2bfloat16(v0 * scale * w[t]);
  xo[t + 256] = __float2bfloat16(v1 * scale * w[t + 256]);
  xo[t + 512] = __float2bfloat16(v2 * scale * w[t + 512]);
}

// causal depthwise conv (DC=4) + bias + silu; input = first DIN cols of xz
__global__ __launch_bounds__(256) void conv_silu_kernel(
    const float* __restrict__ xz, const float* __restrict__ cw,
    const float* __restrict__ cb, float* __restrict__ xb) {
  int idx = blockIdx.x * 256 + threadIdx.x;          // 2048*1536 total
  int row = idx / DIN;                               // b*L + l
  int d = idx - row * DIN;
  int l = row & (LL - 1);
  const float* col = xz + (size_t)row * (2 * DIN) + d;
  float w0 = cw[d * 4 + 0], w1 = cw[d * 4 + 1], w2 = cw[d * 4 + 2],
        w3 = cw[d * 4 + 3];
  float acc = cb[d] + w3 * col[0];
  if (l >= 1) acc += w2 * col[-(2 * DIN)];
  if (l >= 2) acc += w1 * col[-2 * (2 * DIN)];
  if (l >= 3) acc += w0 * col[-3 * (2 * DIN)];
  float sig = 1.0f / (1.0f + __expf(-acc));
  xb[idx] = acc * sig;
}

// ---------------- fp32 GEMM (small shapes: x_proj, dt_proj) ----------------
// C(M x N) = A(M x K) * W(N x K)^T.  EPI: 0 = none, 1 = softplus(acc+bias[n])
__device__ __forceinline__ float softplus_f(float t) {
  return t > 20.0f ? t : log1pf(__expf(t));
}

template <int EPI>
__global__ __launch_bounds__(256) void sgemm_nt(
    const float* __restrict__ A, int lda,
    const float* __restrict__ W, int ldw,
    float* __restrict__ C, int ldc,
    int N, int K, const float* __restrict__ bias) {
  __shared__ float As[16][68];
  __shared__ float Ws[16][68];
  const int tid = threadIdx.x;
  const int tx = tid & 15, ty = tid >> 4;
  const int bm = blockIdx.x, bn = blockIdx.y;
  const int lrow = tid >> 2;          // 0..63
  const int lk4 = (tid & 3) << 2;     // 0,4,8,12
  const float* Aptr = A + (size_t)(bm * 64 + lrow) * lda + lk4;
  const int wrow = bn * 64 + lrow;
  const float* Wptr = W + (size_t)wrow * ldw + lk4;
  const bool wvalid = wrow < N;
  float c[4][4] = {};
  for (int k0 = 0; k0 < K; k0 += 16) {
    float4 a4 = *(const float4*)(Aptr + k0);
    float4 w4 = wvalid ? *(const float4*)(Wptr + k0) : make_float4(0, 0, 0, 0);
    __syncthreads();
    As[lk4 + 0][lrow] = a4.x; As[lk4 + 1][lrow] = a4.y;
    As[lk4 + 2][lrow] = a4.z; As[lk4 + 3][lrow] = a4.w;
    Ws[lk4 + 0][lrow] = w4.x; Ws[lk4 + 1][lrow] = w4.y;
    Ws[lk4 + 2][lrow] = w4.z; Ws[lk4 + 3][lrow] = w4.w;
    __syncthreads();
#pragma unroll
    for (int k = 0; k < 16; k++) {
      float4 a = *(const float4*)&As[k][ty << 2];
      float4 w = *(const float4*)&Ws[k][tx << 2];
      c[0][0] += a.x * w.x; c[0][1] += a.x * w.y; c[0][2] += a.x * w.z; c[0][3] += a.x * w.w;
      c[1][0] += a.y * w.x; c[1][1] += a.y * w.y; c[1][2] += a.y * w.z; c[1][3] += a.y * w.w;
      c[2][0] += a.z * w.x; c[2][1] += a.z * w.y; c[2][2] += a.z * w.z; c[2][3] += a.z * w.w;
      c[3][0] += a.w * w.x; c[3][1] += a.w * w.y; c[3][2] += a.w * w.z; c[3][3] += a.w * w.w;
    }
  }
  const int m0 = bm * 64 + (ty << 2);
  const int n0 = bn * 64 + (tx << 2);
#pragma unroll
  for (int i = 0; i < 4; i++) {
    float* crow = C + (size_t)(m0 + i) * ldc;
#pragma unroll
    for (int j = 0; j < 4; j++) {
      int n = n0 + j;
      if (n < N) {
        float v = c[i][j];
        if constexpr (EPI == 1) v = softplus_f(v + bias[n]);
        crow[n] = v;
      }
    }
  }
}

// ---------------- bf16 MFMA GEMM (m97 structure) ----------------
// C(M x N) = A(M x K)_bf16 * W(N x K)_bf16^T, fp32 out.
// 128x128 tile, BK=32, global_load_lds 16B staging, 4 waves as 2x2 of 64x64.
// Requires: M,N multiples of 128; K multiple of 32; lda/ldw multiples of 8.
// EPI: 0 = none, 2 = C += acc (residual), 3 = acc + bias[n]

__device__ __forceinline__ void gload16(const void* g, void* l) {
  __builtin_amdgcn_global_load_lds(
      (const __attribute__((address_space(1))) void*)g,
      (__attribute__((address_space(3))) void*)l, 16, 0, 0);
}

template <int EPI>
__global__ __launch_bounds__(256) void bgemm_nt(
    const __hip_bfloat16* __restrict__ A, int lda,
    const __hip_bfloat16* __restrict__ W, int ldw,
    float* __restrict__ C, int ldc,
    int K, const float* __restrict__ bias) {
  __shared__ short As[128 * 32];   // 8 KB
  __shared__ short Ws[128 * 32];   // 8 KB
  const int tid = threadIdx.x;
  const int wave = tid >> 6, lane = tid & 63;
  const int wm = wave >> 1, wn = wave & 1;
  const int tileM = blockIdx.x * 128, tileN = blockIdx.y * 128;

  const short* Ag = (const short*)A;
  const short* Wg = (const short*)W;
  // staging: chunk cid covers A-tile row cid>>2, bf16 cols [(cid&3)*8, +8)
  const int cid0 = tid, cid1 = tid + 256;
  const size_t aOff0 = (size_t)(tileM + (cid0 >> 2)) * lda + (cid0 & 3) * 8;
  const size_t aOff1 = (size_t)(tileM + (cid1 >> 2)) * lda + (cid1 & 3) * 8;
  const size_t wOff0 = (size_t)(tileN + (cid0 >> 2)) * ldw + (cid0 & 3) * 8;
  const size_t wOff1 = (size_t)(tileN + (cid1 >> 2)) * ldw + (cid1 & 3) * 8;
  // LDS dst: wave-uniform base + lane*16B (implicit)
  short* AsD0 = As + wave * 512;
  short* AsD1 = As + 2048 + wave * 512;
  short* WsD0 = Ws + wave * 512;
  short* WsD1 = Ws + 2048 + wave * 512;

  const int fr = lane & 15, fq = lane >> 4;
  f32x4 acc[4][4] = {};

  for (int k0 = 0; k0 < K; k0 += 32) {
    gload16(Ag + aOff0 + k0, AsD0);
    gload16(Ag + aOff1 + k0, AsD1);
    gload16(Wg + wOff0 + k0, WsD0);
    gload16(Wg + wOff1 + k0, WsD1);
    __syncthreads();                    // drains vmcnt -> LDS visible
    short8 afr[4], bfr[4];
#pragma unroll
    for (int t = 0; t < 4; t++) {
      afr[t] = *(const short8*)(As + (wm * 64 + t * 16 + fr) * 32 + fq * 8);
      bfr[t] = *(const short8*)(Ws + (wn * 64 + t * 16 + fr) * 32 + fq * 8);
    }
#pragma unroll
    for (int mt = 0; mt < 4; mt++)
#pragma unroll
      for (int nt = 0; nt < 4; nt++)
        acc[mt][nt] = __builtin_amdgcn_mfma_f32_16x16x32_bf16(
            afr[mt], bfr[nt], acc[mt][nt], 0, 0, 0);
    __syncthreads();                    // LDS reads done before next stage
  }

  // C/D layout: col = lane&15, row = (lane>>4)*4 + reg
#pragma unroll
  for (int mt = 0; mt < 4; mt++) {
#pragma unroll
    for (int r = 0; r < 4; r++) {
      int row = tileM + wm * 64 + mt * 16 + fq * 4 + r;
      float* crow = C + (size_t)row * ldc;
#pragma unroll
      for (int nt = 0; nt < 4; nt++) {
        int col = tileN + wn * 64 + nt * 16 + fr;
        float v = acc[mt][nt][r];
        if constexpr (EPI == 2) v += crow[col];
        else if constexpr (EPI == 3) v += bias[col];
        crow[col] = v;
      }
    }
  }
}

// ---------------- chunked selective scan ----------------
// h_t = exp(delta_t * A) * h_{t-1} + delta_t * B_t * u_t  is a linear
// recurrence; chunk-compose with P_chunk = exp(A * sum(delta over chunk)).
// pass1: per chunk, run from h=0 -> q_c (chunk contribution) + sum(delta).
// pass2: serial carry over NCH chunks -> entry state per chunk.
// pass3: re-run each chunk from its entry state, emit gated y (bf16).
// Layout: one channel d per lane (coalesced u/delta/z), 16 states in regs
// (16 independent FMA chains of ILP, no cross-lane ops).

__global__ __launch_bounds__(256) void scan_pass1(
    const float* __restrict__ u,      // xb   (2048 x 1536)
    const float* __restrict__ dlt,    // delta(2048 x 1536)
    const float* __restrict__ xdbl,   // (2048 x 80): B at +48
    const float* __restrict__ A_log,  // layer slice (1536 x 16)
    float* __restrict__ qbuf,         // (B, NCH, DIN, NS)
    float* __restrict__ sdel) {       // (B, NCH, DIN)
  const int d = blockIdx.x * 256 + threadIdx.x;   // 0..1535
  const int c = blockIdx.y;                       // 0..NCH-2
  const int b = blockIdx.z;
  float Ac2[NS];
  {
    const float* ar = A_log + (size_t)d * NS;
#pragma unroll
    for (int j = 0; j < NS; j++) Ac2[j] = -__expf(ar[j]) * 1.44269504f;
  }
  const int l0 = c * CLEN;
  const float* ur = u   + ((size_t)b * LL + l0) * DIN + d;
  const float* dr = dlt + ((size_t)b * LL + l0) * DIN + d;
  const float* br = xdbl + ((size_t)b * LL + l0) * 80 + DTRK;
  float h[NS];
#pragma unroll
  for (int j = 0; j < NS; j++) h[j] = 0.0f;
  float sd = 0.0f;
  for (int t = 0; t < CLEN; t++) {
    float dl = dr[(size_t)t * DIN];
    float ul = ur[(size_t)t * DIN];
    float Bv[NS];
    *(float4*)&Bv[0]  = *(const float4*)(br + (size_t)t * 80);
    *(float4*)&Bv[4]  = *(const float4*)(br + (size_t)t * 80 + 4);
    *(float4*)&Bv[8]  = *(const float4*)(br + (size_t)t * 80 + 8);
    *(float4*)&Bv[12] = *(const float4*)(br + (size_t)t * 80 + 12);
    sd += dl;
    float du = dl * ul;
#pragma unroll
    for (int j = 0; j < NS; j++)
      h[j] = exp2f(dl * Ac2[j]) * h[j] + du * Bv[j];
  }
  float* qo = qbuf + (((size_t)b * NCH + c) * DIN + d) * NS;
#pragma unroll
  for (int j = 0; j < NS; j += 4)
    *(float4*)(qo + j) = make_float4(h[j], h[j + 1], h[j + 2], h[j + 3]);
  sdel[((size_t)b * NCH + c) * DIN + d] = sd;
}

__global__ __launch_bounds__(256) void scan_pass2(
    const float* __restrict__ qbuf, const float* __restrict__ sdel,
    const float* __restrict__ A_log, float* __restrict__ hstart) {
  const int e = blockIdx.x * 256 + threadIdx.x;   // over DIN*NS = 24576
  const int n = e & (NS - 1);
  const int d = e >> 4;
  const int b = blockIdx.y;
  float Ac2 = -__expf(A_log[(size_t)d * NS + n]) * 1.44269504f;
  float h = 0.0f;
  for (int c = 0; c < NCH; c++) {
    hstart[(((size_t)b * NCH + c) * DIN + d) * NS + n] = h;   // state BEFORE chunk c
    if (c + 1 < NCH) {
      float sd = sdel[((size_t)b * NCH + c) * DIN + d];
      float q  = qbuf[(((size_t)b * NCH + c) * DIN + d) * NS + n];
      h = exp2f(Ac2 * sd) * h + q;
    }
  }
}

__global__ __launch_bounds__(256) void scan_pass3(
    const float* __restrict__ u,      // xb
    const float* __restrict__ dlt,    // delta
    const float* __restrict__ xdbl,   // B at +48, C at +64
    const float* __restrict__ xz,     // z at col DIN+d, stride 2*DIN
    const float* __restrict__ A_log,  // layer slice (1536 x 16)
    const float* __restrict__ Dv,     // layer slice (1536)
    const float* __restrict__ hstart, // (B, NCH, DIN, NS)
    __hip_bfloat16* __restrict__ y) { // (2048 x 1536) bf16
  const int d = blockIdx.x * 256 + threadIdx.x;
  const int c = blockIdx.y;
  const int b = blockIdx.z;
  float Ac2[NS];
  {
    const float* ar = A_log + (size_t)d * NS;
#pragma unroll
    for (int j = 0; j < NS; j++) Ac2[j] = -__expf(ar[j]) * 1.44269504f;
  }
  const float Dd = Dv[d];
  float h[NS];
  {
    const float* hs = hstart + (((size_t)b * NCH + c) * DIN + d) * NS;
#pragma unroll
    for (int j = 0; j < NS; j += 4) {
      float4 hv = *(const float4*)(hs + j);
      h[j] = hv.x; h[j + 1] = hv.y; h[j + 2] = hv.z; h[j + 3] = hv.w;
    }
  }
  const int l0 = c * CLEN;
  const float* ur = u   + ((size_t)b * LL + l0) * DIN + d;
  const float* dr = dlt + ((size_t)b * LL + l0) * DIN + d;
  const float* br = xdbl + ((size_t)b * LL + l0) * 80 + DTRK;      // B
  const float* cr = br + NS;                                       // C
  const float* zr = xz + ((size_t)b * LL + l0) * (2 * DIN) + DIN + d;
  __hip_bfloat16* yr = y + ((size_t)b * LL + l0) * DIN + d;
  for (int t = 0; t < CLEN; t++) {
    float dl = dr[(size_t)t * DIN];
    float ul = ur[(size_t)t * DIN];
    float zl = zr[(size_t)t * (2 * DIN)];
    float Bv[NS], Cv[NS];
    *(float4*)&Bv[0]  = *(const float4*)(br + (size_t)t * 80);
    *(float4*)&Bv[4]  = *(const float4*)(br + (size_t)t * 80 + 4);
    *(float4*)&Bv[8]  = *(const float4*)(br + (size_t)t * 80 + 8);
    *(float4*)&Bv[12] = *(const float4*)(br + (size_t)t * 80 + 12);
    *(float4*)&Cv[0]  = *(const float4*)(cr + (size_t)t * 80);
    *(float4*)&Cv[4]  = *(const float4*)(cr + (size_t)t * 80 + 4);
    *(float4*)&Cv[8]  = *(const float4*)(cr + (size_t)t * 80 + 8);
    *(float4*)&Cv[12] = *(const float4*)(cr + (size_t)t * 80 + 12);
    float du = dl * ul;
    float acc = 0.0f;
#pragma unroll
    for (int j = 0; j < NS; j++) {
      h[j] = exp2f(dl * Ac2[j]) * h[j] + du * Bv[j];
      acc += h[j] * Cv[j];
    }
    acc += ul * Dd;
    float sig = 1.0f / (1.0f + __expf(-zl));
    yr[(size_t)t * DIN] = __float2bfloat16(acc * (zl * sig));
  }
}

// ---------------- launch ----------------

extern "C" void kernel_launch(void* const* d_in, const int* in_sizes, int n_in,
                              void* d_out, int out_size, void* d_ws,
                              size_t ws_size, hipStream_t stream) {
  const int*   tokens    = (const int*)d_in[0];
  const float* embedding = (const float*)d_in[1];
  const float* W_out_w   = (const float*)d_in[2];
  const float* W_out_b   = (const float*)d_in[3];
  const float* norm_w    = (const float*)d_in[4];
  const float* in_proj_w = (const float*)d_in[5];
  const float* conv_w    = (const float*)d_in[6];
  const float* conv_b    = (const float*)d_in[7];
  const float* x_proj_w  = (const float*)d_in[8];
  const float* dt_proj_w = (const float*)d_in[9];
  const float* dt_proj_b = (const float*)d_in[10];
  const float* A_log     = (const float*)d_in[11];
  const float* Dvec      = (const float*)d_in[12];
  const float* out_proj_w= (const float*)d_in[13];
  float* out = (float*)d_out;

  float* ws = (float*)d_ws;
  float* x    = ws;                          // 2048*768
  float* xz   = x + (size_t)ROWS * DD;       // 2048*3072
  float* xb   = xz + (size_t)ROWS * 2 * DIN; // 2048*1536
  float* xdbl = xb + (size_t)ROWS * DIN;     // 2048*80
  float* dlt  = xdbl + (size_t)ROWS * 80;    // 2048*1536
  __hip_bfloat16* bfbase = (__hip_bfloat16*)(dlt + (size_t)ROWS * DIN);
  __hip_bfloat16* xnb  = bfbase;                         // 2048*768
  __hip_bfloat16* ybb  = xnb + (size_t)ROWS * DD;        // 2048*1536
  __hip_bfloat16* xbf  = ybb + (size_t)ROWS * DIN;       // 2048*768
  __hip_bfloat16* wInB = xbf + (size_t)ROWS * DD;        // 4*3072*768
  __hip_bfloat16* wOpB = wInB + (size_t)NLAY * 2 * DIN * DD; // 4*768*1536
  __hip_bfloat16* wLgB = wOpB + (size_t)NLAY * DD * DIN; // 32000*768
  // chunked-scan carry buffers (fp32), after the bf16 region
  float* qbuf   = (float*)(wLgB + (size_t)VV * DD);      // B*NCH*DIN*NS
  float* sdel   = qbuf + (size_t)BB * NCH * DIN * NS;    // B*NCH*DIN
  float* hstart = sdel + (size_t)BB * NCH * DIN;         // B*NCH*DIN*NS

  // weight conversions (every call; same work each call)
  {
    int n4 = NLAY * 2 * DIN * DD / 4;
    cvt_bf16_kernel<<<(n4 + 255) / 256, 256, 0, stream>>>(in_proj_w, wInB, n4);
    n4 = NLAY * DD * DIN / 4;
    cvt_bf16_kernel<<<(n4 + 255) / 256, 256, 0, stream>>>(out_proj_w, wOpB, n4);
    n4 = VV * DD / 4;
    cvt_bf16_kernel<<<(n4 + 255) / 256, 256, 0, stream>>>(W_out_w, wLgB, n4);
  }

  embed_kernel<<<ROWS * DD / 256, 256, 0, stream>>>(tokens, embedding, x);

  for (int i = 0; i < NLAY; i++) {
    rmsnorm_kernel<<<ROWS, 256, 0, stream>>>(x, norm_w + (size_t)i * DD, xnb);
    // xz = xn @ in_proj^T   (2048x768)x(3072x768)^T  [bf16 MFMA]
    bgemm_nt<0><<<dim3(16, 24), 256, 0, stream>>>(
        xnb, DD, wInB + (size_t)i * 2 * DIN * DD, DD, xz, 2 * DIN, DD,
        nullptr);
    // xb = silu(conv(xz[:, :DIN]))
    conv_silu_kernel<<<ROWS * DIN / 256, 256, 0, stream>>>(
        xz, conv_w + (size_t)i * DIN * DCV, conv_b + (size_t)i * DIN, xb);
    // x_dbl = xb @ x_proj^T (2048x1536)x(80x1536)^T  [fp32]
    sgemm_nt<0><<<dim3(32, 2), 256, 0, stream>>>(
        xb, DIN, x_proj_w + (size_t)i * (DTRK + 2 * NS) * DIN, DIN, xdbl,
        DTRK + 2 * NS, DTRK + 2 * NS, DIN, nullptr);
    // delta = softplus(dt @ dt_proj^T + dt_b) (2048x48)x(1536x48)^T [fp32]
    sgemm_nt<1><<<dim3(32, 24), 256, 0, stream>>>(
        xdbl, DTRK + 2 * NS, dt_proj_w + (size_t)i * DIN * DTRK, DTRK, dlt,
        DIN, DIN, DTRK, dt_proj_b + (size_t)i * DIN);
    // selective scan + gating -> ybb (bf16), chunked 3-pass
    const float* Ai = A_log + (size_t)i * DIN * NS;
    scan_pass1<<<dim3(DIN / 256, NCH - 1, BB), 256, 0, stream>>>(
        xb, dlt, xdbl, Ai, qbuf, sdel);
    scan_pass2<<<dim3(DIN * NS / 256, BB), 256, 0, stream>>>(
        qbuf, sdel, Ai, hstart);
    scan_pass3<<<dim3(DIN / 256, NCH, BB), 256, 0, stream>>>(
        xb, dlt, xdbl, xz, Ai, Dvec + (size_t)i * DIN, hstart, ybb);
    // x += yb @ out_proj^T  (2048x1536)x(768x1536)^T  [bf16 MFMA]
    bgemm_nt<2><<<dim3(16, 6), 256, 0, stream>>>(
        ybb, DIN, wOpB + (size_t)i * DD * DIN, DIN, x, DD, DIN, nullptr);
  }

  // logits = x @ W_out^T + b  (2048x768)x(32000x768)^T  [bf16 MFMA]
  {
    int n4 = ROWS * DD / 4;
    cvt_bf16_kernel<<<(n4 + 255) / 256, 256, 0, stream>>>(x, xbf, n4);
  }
  bgemm_nt<3><<<dim3(16, 250), 256, 0, stream>>>(
      xbf, DD, wLgB, DD, out, VV, DD, W_out_b);
}

// Round 2
// 1397.897 us; speedup vs baseline: 2.0011x; 1.1588x over previous
//
#include <hip/hip_runtime.h>
#include <hip/hip_bf16.h>
#include <math.h>

// Problem constants
#define BB   2
#define LL   1024
#define DD   768
#define DIN  1536      // d_inner
#define NS   16        // d_state
#define DCV  4         // d_conv
#define DTRK 48        // dt_rank
#define NLAY 4
#define VV   32000
#define ROWS (BB*LL)   // 2048

// chunked scan
#define NCH  32        // number of chunks over L
#define CLEN (LL/NCH)  // 32 steps per chunk

typedef __attribute__((ext_vector_type(8))) short short8;
typedef __attribute__((ext_vector_type(4))) float f32x4;

// ---------------- elementwise / small kernels ----------------

__global__ __launch_bounds__(256) void embed_kernel(
    const int* __restrict__ tok, const float* __restrict__ emb,
    float* __restrict__ x) {
  int idx = blockIdx.x * 256 + threadIdx.x;          // 2048*768 total
  int row = idx / DD, c = idx - row * DD;
  x[idx] = emb[(size_t)tok[row] * DD + c];
}

__device__ __forceinline__ void cvt4_bf16(const float* __restrict__ in,
                                          __hip_bfloat16* __restrict__ out,
                                          int i) {
  float4 v = ((const float4*)in)[i];
  __hip_bfloat16 t0 = __float2bfloat16(v.x);
  __hip_bfloat16 t1 = __float2bfloat16(v.y);
  __hip_bfloat16 t2 = __float2bfloat16(v.z);
  __hip_bfloat16 t3 = __float2bfloat16(v.w);
  ushort4 pack = make_ushort4(*(unsigned short*)&t0, *(unsigned short*)&t1,
                              *(unsigned short*)&t2, *(unsigned short*)&t3);
  ((ushort4*)out)[i] = pack;
}

// fp32 -> bf16, 4 elements/thread (n divisible by 4)
__global__ __launch_bounds__(256) void cvt_bf16_kernel(
    const float* __restrict__ in, __hip_bfloat16* __restrict__ out, int n4) {
  int i = blockIdx.x * 256 + threadIdx.x;
  if (i >= n4) return;
  cvt4_bf16(in, out, i);
}

// three conversions in one launch (weight tensors), grid-stride
__global__ __launch_bounds__(256) void cvt3_bf16_kernel(
    const float* __restrict__ i0, __hip_bfloat16* __restrict__ o0, int n0,
    const float* __restrict__ i1, __hip_bfloat16* __restrict__ o1, int n1,
    const float* __restrict__ i2, __hip_bfloat16* __restrict__ o2, int n2) {
  int start = blockIdx.x * 256 + threadIdx.x;
  int stride = gridDim.x * 256;
  for (int j = start; j < n0; j += stride) cvt4_bf16(i0, o0, j);
  for (int j = start; j < n1; j += stride) cvt4_bf16(i1, o1, j);
  for (int j = start; j < n2; j += stride) cvt4_bf16(i2, o2, j);
}

__global__ __launch_bounds__(256) void zero_kernel(float* __restrict__ p,
                                                   int n) {
  int i = blockIdx.x * 256 + threadIdx.x;
  if (i < n) p[i] = 0.0f;
}

__global__ __launch_bounds__(256) void rmsnorm_kernel(
    const float* __restrict__ x, const float* __restrict__ w,
    __hip_bfloat16* __restrict__ xn) {
  int row = blockIdx.x;
  int t = threadIdx.x;
  const float* xr = x + (size_t)row * DD;
  float v0 = xr[t], v1 = xr[t + 256], v2 = xr[t + 512];
  float ss = v0 * v0 + v1 * v1 + v2 * v2;
#pragma unroll
  for (int off = 32; off > 0; off >>= 1) ss += __shfl_down(ss, off);
  __shared__ float sred[4];
  if ((t & 63) == 0) sred[t >> 6] = ss;
  __syncthreads();
  float tot = sred[0] + sred[1] + sred[2] + sred[3];
  float scale = rsqrtf(tot * (1.0f / DD) + 1e-5f);
  __hip_bfloat16* xo = xn + (size_t)row * DD;
  xo[t]       = __float2bfloat16(v0 * scale * w[t]);
  xo[t + 256] = __float2bfloat16(v1 * scale * w[t + 256]);
  xo[t + 512] = __float2bfloat16(v2 * scale * w[t + 512]);
}

// causal depthwise conv (DC=4) + bias + silu; input = first DIN cols of xz
// 4 channels per thread, float4 loads/stores.
__global__ __launch_bounds__(256) void conv_silu_kernel(
    const float* __restrict__ xz, const float* __restrict__ cw,
    const float* __restrict__ cb, float* __restrict__ xb) {
  int idx = blockIdx.x * 256 + threadIdx.x;          // ROWS*DIN/4 total
  int row = idx / (DIN / 4);                         // b*L + l
  int d4 = idx - row * (DIN / 4);
  int d = d4 << 2;
  int l = row & (LL - 1);
  const float* col = xz + (size_t)row * (2 * DIN) + d;
  float4 x0 = *(const float4*)col;
  float4 x1 = make_float4(0, 0, 0, 0), x2 = x1, x3 = x1;
  if (l >= 1) x1 = *(const float4*)(col - 2 * DIN);
  if (l >= 2) x2 = *(const float4*)(col - 4 * DIN);
  if (l >= 3) x3 = *(const float4*)(col - 6 * DIN);
  float4 bb = *(const float4*)(cb + d);
  // cw[d][k]: k=3 is current tap, k=0 oldest
  float4 wa = *(const float4*)(cw + (size_t)(d + 0) * 4);
  float4 wb = *(const float4*)(cw + (size_t)(d + 1) * 4);
  float4 wc = *(const float4*)(cw + (size_t)(d + 2) * 4);
  float4 wd = *(const float4*)(cw + (size_t)(d + 3) * 4);
  float4 r;
  r.x = bb.x + wa.w * x0.x + wa.z * x1.x + wa.y * x2.x + wa.x * x3.x;
  r.y = bb.y + wb.w * x0.y + wb.z * x1.y + wb.y * x2.y + wb.x * x3.y;
  r.z = bb.z + wc.w * x0.z + wc.z * x1.z + wc.y * x2.z + wc.x * x3.z;
  r.w = bb.w + wd.w * x0.w + wd.z * x1.w + wd.y * x2.w + wd.x * x3.w;
  r.x = r.x / (1.0f + __expf(-r.x));
  r.y = r.y / (1.0f + __expf(-r.y));
  r.z = r.z / (1.0f + __expf(-r.z));
  r.w = r.w / (1.0f + __expf(-r.w));
  *(float4*)(xb + (size_t)row * DIN + d) = r;
}

// ---------------- fp32 GEMM (small shapes: x_proj, dt_proj) ----------------
// C(M x N) = A(M x K) * W(N x K)^T.  EPI: 0 = none, 1 = softplus(acc+bias[n])
// gridDim.z > 1 => split-K: each z-slice does K/gridDim.z and atomicAdds into
// a pre-zeroed C (EPI must be 0 in that case).
__device__ __forceinline__ float softplus_f(float t) {
  return t > 20.0f ? t : log1pf(__expf(t));
}

template <int EPI>
__global__ __launch_bounds__(256) void sgemm_nt(
    const float* __restrict__ A, int lda,
    const float* __restrict__ W, int ldw,
    float* __restrict__ C, int ldc,
    int N, int K, const float* __restrict__ bias) {
  __shared__ float As[16][68];
  __shared__ float Ws[16][68];
  const int tid = threadIdx.x;
  const int tx = tid & 15, ty = tid >> 4;
  const int bm = blockIdx.x, bn = blockIdx.y;
  const int kLen = K / gridDim.z;
  const int kBegin = blockIdx.z * kLen;
  const int kEnd = kBegin + kLen;
  const int lrow = tid >> 2;          // 0..63
  const int lk4 = (tid & 3) << 2;     // 0,4,8,12
  const float* Aptr = A + (size_t)(bm * 64 + lrow) * lda + lk4;
  const int wrow = bn * 64 + lrow;
  const float* Wptr = W + (size_t)wrow * ldw + lk4;
  const bool wvalid = wrow < N;
  float c[4][4] = {};
  for (int k0 = kBegin; k0 < kEnd; k0 += 16) {
    float4 a4 = *(const float4*)(Aptr + k0);
    float4 w4 = wvalid ? *(const float4*)(Wptr + k0) : make_float4(0, 0, 0, 0);
    __syncthreads();
    As[lk4 + 0][lrow] = a4.x; As[lk4 + 1][lrow] = a4.y;
    As[lk4 + 2][lrow] = a4.z; As[lk4 + 3][lrow] = a4.w;
    Ws[lk4 + 0][lrow] = w4.x; Ws[lk4 + 1][lrow] = w4.y;
    Ws[lk4 + 2][lrow] = w4.z; Ws[lk4 + 3][lrow] = w4.w;
    __syncthreads();
#pragma unroll
    for (int k = 0; k < 16; k++) {
      float4 a = *(const float4*)&As[k][ty << 2];
      float4 w = *(const float4*)&Ws[k][tx << 2];
      c[0][0] += a.x * w.x; c[0][1] += a.x * w.y; c[0][2] += a.x * w.z; c[0][3] += a.x * w.w;
      c[1][0] += a.y * w.x; c[1][1] += a.y * w.y; c[1][2] += a.y * w.z; c[1][3] += a.y * w.w;
      c[2][0] += a.z * w.x; c[2][1] += a.z * w.y; c[2][2] += a.z * w.z; c[2][3] += a.z * w.w;
      c[3][0] += a.w * w.x; c[3][1] += a.w * w.y; c[3][2] += a.w * w.z; c[3][3] += a.w * w.w;
    }
  }
  const int m0 = bm * 64 + (ty << 2);
  const int n0 = bn * 64 + (tx << 2);
  const bool split = gridDim.z > 1;
#pragma unroll
  for (int i = 0; i < 4; i++) {
    float* crow = C + (size_t)(m0 + i) * ldc;
#pragma unroll
    for (int j = 0; j < 4; j++) {
      int n = n0 + j;
      if (n < N) {
        float v = c[i][j];
        if constexpr (EPI == 1) v = softplus_f(v + bias[n]);
        if (split) atomicAdd(&crow[n], v);
        else crow[n] = v;
      }
    }
  }
}

// ---------------- bf16 MFMA GEMM (m97 structure) ----------------
// C(M x N) = A(M x K)_bf16 * W(N x K)_bf16^T, fp32 out.
// 128x128 tile, BK=32, global_load_lds 16B staging, 4 waves as 2x2 of 64x64.
// XCD-aware block swizzle (T1): blocks sharing a W-panel land on one XCD's L2.
// Requires: M,N multiples of 128; K multiple of 32; lda/ldw multiples of 8.
// EPI: 0 = none, 2 = C += acc (residual), 3 = acc + bias[n]

__device__ __forceinline__ void gload16(const void* g, void* l) {
  __builtin_amdgcn_global_load_lds(
      (const __attribute__((address_space(1))) void*)g,
      (__attribute__((address_space(3))) void*)l, 16, 0, 0);
}

template <int EPI>
__global__ __launch_bounds__(256) void bgemm_nt(
    const __hip_bfloat16* __restrict__ A, int lda,
    const __hip_bfloat16* __restrict__ W, int ldw,
    float* __restrict__ C, int ldc,
    int K, const float* __restrict__ bias) {
  __shared__ short As[128 * 32];   // 8 KB
  __shared__ short Ws[128 * 32];   // 8 KB
  const int tid = threadIdx.x;
  const int wave = tid >> 6, lane = tid & 63;
  const int wm = wave >> 1, wn = wave & 1;

  // XCD swizzle: hardware assigns XCD = flat_dispatch_id % 8; remap so each
  // XCD owns a contiguous range of tiles (contiguous N-panels -> L2 reuse).
  const int nbx = gridDim.x;
  const int nwg = nbx * gridDim.y;
  int flat = blockIdx.y * nbx + blockIdx.x;
  if ((nwg & 7) == 0) {
    int chunk = nwg >> 3;
    flat = (flat & 7) * chunk + (flat >> 3);
  }
  const int tileM = (flat % nbx) * 128, tileN = (flat / nbx) * 128;

  const short* Ag = (const short*)A;
  const short* Wg = (const short*)W;
  // staging: chunk cid covers A-tile row cid>>2, bf16 cols [(cid&3)*8, +8)
  const int cid0 = tid, cid1 = tid + 256;
  const size_t aOff0 = (size_t)(tileM + (cid0 >> 2)) * lda + (cid0 & 3) * 8;
  const size_t aOff1 = (size_t)(tileM + (cid1 >> 2)) * lda + (cid1 & 3) * 8;
  const size_t wOff0 = (size_t)(tileN + (cid0 >> 2)) * ldw + (cid0 & 3) * 8;
  const size_t wOff1 = (size_t)(tileN + (cid1 >> 2)) * ldw + (cid1 & 3) * 8;
  // LDS dst: wave-uniform base + lane*16B (implicit)
  short* AsD0 = As + wave * 512;
  short* AsD1 = As + 2048 + wave * 512;
  short* WsD0 = Ws + wave * 512;
  short* WsD1 = Ws + 2048 + wave * 512;

  const int fr = lane & 15, fq = lane >> 4;
  f32x4 acc[4][4] = {};

  for (int k0 = 0; k0 < K; k0 += 32) {
    gload16(Ag + aOff0 + k0, AsD0);
    gload16(Ag + aOff1 + k0, AsD1);
    gload16(Wg + wOff0 + k0, WsD0);
    gload16(Wg + wOff1 + k0, WsD1);
    __syncthreads();                    // drains vmcnt -> LDS visible
    short8 afr[4], bfr[4];
#pragma unroll
    for (int t = 0; t < 4; t++) {
      afr[t] = *(const short8*)(As + (wm * 64 + t * 16 + fr) * 32 + fq * 8);
      bfr[t] = *(const short8*)(Ws + (wn * 64 + t * 16 + fr) * 32 + fq * 8);
    }
#pragma unroll
    for (int mt = 0; mt < 4; mt++)
#pragma unroll
      for (int nt = 0; nt < 4; nt++)
        acc[mt][nt] = __builtin_amdgcn_mfma_f32_16x16x32_bf16(
            afr[mt], bfr[nt], acc[mt][nt], 0, 0, 0);
    __syncthreads();                    // LDS reads done before next stage
  }

  // C/D layout: col = lane&15, row = (lane>>4)*4 + reg
#pragma unroll
  for (int mt = 0; mt < 4; mt++) {
#pragma unroll
    for (int r = 0; r < 4; r++) {
      int row = tileM + wm * 64 + mt * 16 + fq * 4 + r;
      float* crow = C + (size_t)row * ldc;
#pragma unroll
      for (int nt = 0; nt < 4; nt++) {
        int col = tileN + wn * 64 + nt * 16 + fr;
        float v = acc[mt][nt][r];
        if constexpr (EPI == 2) v += crow[col];
        else if constexpr (EPI == 3) v += bias[col];
        crow[col] = v;
      }
    }
  }
}

// ---------------- chunked selective scan ----------------
// h_t = exp(delta_t * A) * h_{t-1} + delta_t * B_t * u_t  is a linear
// recurrence; chunk-compose with P_chunk = exp(A * sum(delta over chunk)).
// pass1: per chunk, run from h=0 -> q_c (chunk contribution) + sum(delta).
// pass2: serial carry over NCH chunks -> entry state per chunk.
// pass3: re-run each chunk from its entry state, emit gated y (bf16).
// Layout: one channel d per lane (coalesced u/delta/z), 16 states in regs
// (16 independent FMA chains of ILP, no cross-lane ops).

__global__ __launch_bounds__(256) void scan_pass1(
    const float* __restrict__ u,      // xb   (2048 x 1536)
    const float* __restrict__ dlt,    // delta(2048 x 1536)
    const float* __restrict__ xdbl,   // (2048 x 80): B at +48
    const float* __restrict__ A_log,  // layer slice (1536 x 16)
    float* __restrict__ qbuf,         // (B, NCH, DIN, NS)
    float* __restrict__ sdel) {       // (B, NCH, DIN)
  const int d = blockIdx.x * 256 + threadIdx.x;   // 0..1535
  const int c = blockIdx.y;                       // 0..NCH-2
  const int b = blockIdx.z;
  float Ac2[NS];
  {
    const float* ar = A_log + (size_t)d * NS;
#pragma unroll
    for (int j = 0; j < NS; j++) Ac2[j] = -__expf(ar[j]) * 1.44269504f;
  }
  const int l0 = c * CLEN;
  const float* ur = u   + ((size_t)b * LL + l0) * DIN + d;
  const float* dr = dlt + ((size_t)b * LL + l0) * DIN + d;
  const float* br = xdbl + ((size_t)b * LL + l0) * 80 + DTRK;
  float h[NS];
#pragma unroll
  for (int j = 0; j < NS; j++) h[j] = 0.0f;
  float sd = 0.0f;
  for (int t = 0; t < CLEN; t++) {
    float dl = dr[(size_t)t * DIN];
    float ul = ur[(size_t)t * DIN];
    float Bv[NS];
    *(float4*)&Bv[0]  = *(const float4*)(br + (size_t)t * 80);
    *(float4*)&Bv[4]  = *(const float4*)(br + (size_t)t * 80 + 4);
    *(float4*)&Bv[8]  = *(const float4*)(br + (size_t)t * 80 + 8);
    *(float4*)&Bv[12] = *(const float4*)(br + (size_t)t * 80 + 12);
    sd += dl;
    float du = dl * ul;
#pragma unroll
    for (int j = 0; j < NS; j++)
      h[j] = exp2f(dl * Ac2[j]) * h[j] + du * Bv[j];
  }
  float* qo = qbuf + (((size_t)b * NCH + c) * DIN + d) * NS;
#pragma unroll
  for (int j = 0; j < NS; j += 4)
    *(float4*)(qo + j) = make_float4(h[j], h[j + 1], h[j + 2], h[j + 3]);
  sdel[((size_t)b * NCH + c) * DIN + d] = sd;
}

__global__ __launch_bounds__(256) void scan_pass2(
    const float* __restrict__ qbuf, const float* __restrict__ sdel,
    const float* __restrict__ A_log, float* __restrict__ hstart) {
  const int e = blockIdx.x * 256 + threadIdx.x;   // over DIN*NS = 24576
  const int n = e & (NS - 1);
  const int d = e >> 4;
  const int b = blockIdx.y;
  float Ac2 = -__expf(A_log[(size_t)d * NS + n]) * 1.44269504f;
  float h = 0.0f;
  for (int c = 0; c < NCH; c++) {
    hstart[(((size_t)b * NCH + c) * DIN + d) * NS + n] = h;   // state BEFORE chunk c
    if (c + 1 < NCH) {
      float sd = sdel[((size_t)b * NCH + c) * DIN + d];
      float q  = qbuf[(((size_t)b * NCH + c) * DIN + d) * NS + n];
      h = exp2f(Ac2 * sd) * h + q;
    }
  }
}

__global__ __launch_bounds__(256) void scan_pass3(
    const float* __restrict__ u,      // xb
    const float* __restrict__ dlt,    // delta
    const float* __restrict__ xdbl,   // B at +48, C at +64
    const float* __restrict__ xz,     // z at col DIN+d, stride 2*DIN
    const float* __restrict__ A_log,  // layer slice (1536 x 16)
    const float* __restrict__ Dv,     // layer slice (1536)
    const float* __restrict__ hstart, // (B, NCH, DIN, NS)
    __hip_bfloat16* __restrict__ y) { // (2048 x 1536) bf16
  const int d = blockIdx.x * 256 + threadIdx.x;
  const int c = blockIdx.y;
  const int b = blockIdx.z;
  float Ac2[NS];
  {
    const float* ar = A_log + (size_t)d * NS;
#pragma unroll
    for (int j = 0; j < NS; j++) Ac2[j] = -__expf(ar[j]) * 1.44269504f;
  }
  const float Dd = Dv[d];
  float h[NS];
  {
    const float* hs = hstart + (((size_t)b * NCH + c) * DIN + d) * NS;
#pragma unroll
    for (int j = 0; j < NS; j += 4) {
      float4 hv = *(const float4*)(hs + j);
      h[j] = hv.x; h[j + 1] = hv.y; h[j + 2] = hv.z; h[j + 3] = hv.w;
    }
  }
  const int l0 = c * CLEN;
  const float* ur = u   + ((size_t)b * LL + l0) * DIN + d;
  const float* dr = dlt + ((size_t)b * LL + l0) * DIN + d;
  const float* br = xdbl + ((size_t)b * LL + l0) * 80 + DTRK;      // B
  const float* cr = br + NS;                                       // C
  const float* zr = xz + ((size_t)b * LL + l0) * (2 * DIN) + DIN + d;
  __hip_bfloat16* yr = y + ((size_t)b * LL + l0) * DIN + d;
  for (int t = 0; t < CLEN; t++) {
    float dl = dr[(size_t)t * DIN];
    float ul = ur[(size_t)t * DIN];
    float zl = zr[(size_t)t * (2 * DIN)];
    float Bv[NS], Cv[NS];
    *(float4*)&Bv[0]  = *(const float4*)(br + (size_t)t * 80);
    *(float4*)&Bv[4]  = *(const float4*)(br + (size_t)t * 80 + 4);
    *(float4*)&Bv[8]  = *(const float4*)(br + (size_t)t * 80 + 8);
    *(float4*)&Bv[12] = *(const float4*)(br + (size_t)t * 80 + 12);
    *(float4*)&Cv[0]  = *(const float4*)(cr + (size_t)t * 80);
    *(float4*)&Cv[4]  = *(const float4*)(cr + (size_t)t * 80 + 4);
    *(float4*)&Cv[8]  = *(const float4*)(cr + (size_t)t * 80 + 8);
    *(float4*)&Cv[12] = *(const float4*)(cr + (size_t)t * 80 + 12);
    float du = dl * ul;
    float acc = 0.0f;
#pragma unroll
    for (int j = 0; j < NS; j++) {
      h[j] = exp2f(dl * Ac2[j]) * h[j] + du * Bv[j];
      acc += h[j] * Cv[j];
    }
    acc += ul * Dd;
    float sig = 1.0f / (1.0f + __expf(-zl));
    yr[(size_t)t * DIN] = __float2bfloat16(acc * (zl * sig));
  }
}

// ---------------- launch ----------------

extern "C" void kernel_launch(void* const* d_in, const int* in_sizes, int n_in,
                              void* d_out, int out_size, void* d_ws,
                              size_t ws_size, hipStream_t stream) {
  const int*   tokens    = (const int*)d_in[0];
  const float* embedding = (const float*)d_in[1];
  const float* W_out_w   = (const float*)d_in[2];
  const float* W_out_b   = (const float*)d_in[3];
  const float* norm_w    = (const float*)d_in[4];
  const float* in_proj_w = (const float*)d_in[5];
  const float* conv_w    = (const float*)d_in[6];
  const float* conv_b    = (const float*)d_in[7];
  const float* x_proj_w  = (const float*)d_in[8];
  const float* dt_proj_w = (const float*)d_in[9];
  const float* dt_proj_b = (const float*)d_in[10];
  const float* A_log     = (const float*)d_in[11];
  const float* Dvec      = (const float*)d_in[12];
  const float* out_proj_w= (const float*)d_in[13];
  float* out = (float*)d_out;

  float* ws = (float*)d_ws;
  float* x    = ws;                          // 2048*768
  float* xz   = x + (size_t)ROWS * DD;       // 2048*3072
  float* xb   = xz + (size_t)ROWS * 2 * DIN; // 2048*1536
  float* xdbl = xb + (size_t)ROWS * DIN;     // 2048*80
  float* dlt  = xdbl + (size_t)ROWS * 80;    // 2048*1536
  __hip_bfloat16* bfbase = (__hip_bfloat16*)(dlt + (size_t)ROWS * DIN);
  __hip_bfloat16* xnb  = bfbase;                         // 2048*768
  __hip_bfloat16* ybb  = xnb + (size_t)ROWS * DD;        // 2048*1536
  __hip_bfloat16* xbf  = ybb + (size_t)ROWS * DIN;       // 2048*768
  __hip_bfloat16* wInB = xbf + (size_t)ROWS * DD;        // 4*3072*768
  __hip_bfloat16* wOpB = wInB + (size_t)NLAY * 2 * DIN * DD; // 4*768*1536
  __hip_bfloat16* wLgB = wOpB + (size_t)NLAY * DD * DIN; // 32000*768
  // chunked-scan carry buffers (fp32), after the bf16 region
  float* qbuf   = (float*)(wLgB + (size_t)VV * DD);      // B*NCH*DIN*NS
  float* sdel   = qbuf + (size_t)BB * NCH * DIN * NS;    // B*NCH*DIN
  float* hstart = sdel + (size_t)BB * NCH * DIN;         // B*NCH*DIN*NS

  // weight conversions (every call; same work each call) -- one launch
  cvt3_bf16_kernel<<<2048, 256, 0, stream>>>(
      in_proj_w, wInB, NLAY * 2 * DIN * DD / 4,
      out_proj_w, wOpB, NLAY * DD * DIN / 4,
      W_out_w, wLgB, VV * DD / 4);

  embed_kernel<<<ROWS * DD / 256, 256, 0, stream>>>(tokens, embedding, x);

  for (int i = 0; i < NLAY; i++) {
    rmsnorm_kernel<<<ROWS, 256, 0, stream>>>(x, norm_w + (size_t)i * DD, xnb);
    // xz = xn @ in_proj^T   (2048x768)x(3072x768)^T  [bf16 MFMA]
    bgemm_nt<0><<<dim3(16, 24), 256, 0, stream>>>(
        xnb, DD, wInB + (size_t)i * 2 * DIN * DD, DD, xz, 2 * DIN, DD,
        nullptr);
    // xb = silu(conv(xz[:, :DIN]))
    conv_silu_kernel<<<ROWS * DIN / 4 / 256, 256, 0, stream>>>(
        xz, conv_w + (size_t)i * DIN * DCV, conv_b + (size_t)i * DIN, xb);
    // x_dbl = xb @ x_proj^T (2048x1536)x(80x1536)^T  [fp32, split-K x8]
    zero_kernel<<<ROWS * 80 / 256, 256, 0, stream>>>(xdbl, ROWS * 80);
    sgemm_nt<0><<<dim3(32, 2, 8), 256, 0, stream>>>(
        xb, DIN, x_proj_w + (size_t)i * (DTRK + 2 * NS) * DIN, DIN, xdbl,
        DTRK + 2 * NS, DTRK + 2 * NS, DIN, nullptr);
    // delta = softplus(dt @ dt_proj^T + dt_b) (2048x48)x(1536x48)^T [fp32]
    sgemm_nt<1><<<dim3(32, 24), 256, 0, stream>>>(
        xdbl, DTRK + 2 * NS, dt_proj_w + (size_t)i * DIN * DTRK, DTRK, dlt,
        DIN, DIN, DTRK, dt_proj_b + (size_t)i * DIN);
    // selective scan + gating -> ybb (bf16), chunked 3-pass
    const float* Ai = A_log + (size_t)i * DIN * NS;
    scan_pass1<<<dim3(DIN / 256, NCH - 1, BB), 256, 0, stream>>>(
        xb, dlt, xdbl, Ai, qbuf, sdel);
    scan_pass2<<<dim3(DIN * NS / 256, BB), 256, 0, stream>>>(
        qbuf, sdel, Ai, hstart);
    scan_pass3<<<dim3(DIN / 256, NCH, BB), 256, 0, stream>>>(
        xb, dlt, xdbl, xz, Ai, Dvec + (size_t)i * DIN, hstart, ybb);
    // x += yb @ out_proj^T  (2048x1536)x(768x1536)^T  [bf16 MFMA]
    bgemm_nt<2><<<dim3(16, 6), 256, 0, stream>>>(
        ybb, DIN, wOpB + (size_t)i * DD * DIN, DIN, x, DD, DIN, nullptr);
  }

  // logits = x @ W_out^T + b  (2048x768)x(32000x768)^T  [bf16 MFMA]
  {
    int n4 = ROWS * DD / 4;
    cvt_bf16_kernel<<<(n4 + 255) / 256, 256, 0, stream>>>(x, xbf, n4);
  }
  bgemm_nt<3><<<dim3(16, 250), 256, 0, stream>>>(
      xbf, DD, wLgB, DD, out, VV, DD, W_out_b);
}

// Round 3
// 1349.497 us; speedup vs baseline: 2.0729x; 1.0359x over previous
//
#include <hip/hip_runtime.h>
#include <hip/hip_bf16.h>
#include <math.h>

// Problem constants
#define BB   2
#define LL   1024
#define DD   768
#define DIN  1536      // d_inner
#define NS   16        // d_state
#define DCV  4         // d_conv
#define DTRK 48        // dt_rank
#define NLAY 4
#define VV   32000
#define ROWS (BB*LL)   // 2048

// chunked scan
#define NCH  32        // number of chunks over L
#define CLEN (LL/NCH)  // 32 steps per chunk

typedef __attribute__((ext_vector_type(8))) short short8;
typedef __attribute__((ext_vector_type(4))) float f32x4;

// ---------------- elementwise / small kernels ----------------

__global__ __launch_bounds__(256) void embed_kernel(
    const int* __restrict__ tok, const float* __restrict__ emb,
    float* __restrict__ x) {
  int idx = blockIdx.x * 256 + threadIdx.x;          // 2048*768 total
  int row = idx / DD, c = idx - row * DD;
  x[idx] = emb[(size_t)tok[row] * DD + c];
}

__device__ __forceinline__ void cvt4_bf16(const float* __restrict__ in,
                                          __hip_bfloat16* __restrict__ out,
                                          int i) {
  float4 v = ((const float4*)in)[i];
  __hip_bfloat16 t0 = __float2bfloat16(v.x);
  __hip_bfloat16 t1 = __float2bfloat16(v.y);
  __hip_bfloat16 t2 = __float2bfloat16(v.z);
  __hip_bfloat16 t3 = __float2bfloat16(v.w);
  ushort4 pack = make_ushort4(*(unsigned short*)&t0, *(unsigned short*)&t1,
                              *(unsigned short*)&t2, *(unsigned short*)&t3);
  ((ushort4*)out)[i] = pack;
}

// fp32 -> bf16, 4 elements/thread (n divisible by 4)
__global__ __launch_bounds__(256) void cvt_bf16_kernel(
    const float* __restrict__ in, __hip_bfloat16* __restrict__ out, int n4) {
  int i = blockIdx.x * 256 + threadIdx.x;
  if (i >= n4) return;
  cvt4_bf16(in, out, i);
}

// three conversions in one launch (weight tensors), grid-stride
__global__ __launch_bounds__(256) void cvt3_bf16_kernel(
    const float* __restrict__ i0, __hip_bfloat16* __restrict__ o0, int n0,
    const float* __restrict__ i1, __hip_bfloat16* __restrict__ o1, int n1,
    const float* __restrict__ i2, __hip_bfloat16* __restrict__ o2, int n2) {
  int start = blockIdx.x * 256 + threadIdx.x;
  int stride = gridDim.x * 256;
  for (int j = start; j < n0; j += stride) cvt4_bf16(i0, o0, j);
  for (int j = start; j < n1; j += stride) cvt4_bf16(i1, o1, j);
  for (int j = start; j < n2; j += stride) cvt4_bf16(i2, o2, j);
}

__global__ __launch_bounds__(256) void zero_kernel(float* __restrict__ p,
                                                   int n) {
  int i = blockIdx.x * 256 + threadIdx.x;
  if (i < n) p[i] = 0.0f;
}

__global__ __launch_bounds__(256) void rmsnorm_kernel(
    const float* __restrict__ x, const float* __restrict__ w,
    __hip_bfloat16* __restrict__ xn) {
  int row = blockIdx.x;
  int t = threadIdx.x;
  const float* xr = x + (size_t)row * DD;
  float v0 = xr[t], v1 = xr[t + 256], v2 = xr[t + 512];
  float ss = v0 * v0 + v1 * v1 + v2 * v2;
#pragma unroll
  for (int off = 32; off > 0; off >>= 1) ss += __shfl_down(ss, off);
  __shared__ float sred[4];
  if ((t & 63) == 0) sred[t >> 6] = ss;
  __syncthreads();
  float tot = sred[0] + sred[1] + sred[2] + sred[3];
  float scale = rsqrtf(tot * (1.0f / DD) + 1e-5f);
  __hip_bfloat16* xo = xn + (size_t)row * DD;
  xo[t]       = __float2bfloat16(v0 * scale * w[t]);
  xo[t + 256] = __float2bfloat16(v1 * scale * w[t + 256]);
  xo[t + 512] = __float2bfloat16(v2 * scale * w[t + 512]);
}

// causal depthwise conv (DC=4) + bias + silu; input = first DIN cols of xz
// 4 channels per thread, float4 loads/stores.
__global__ __launch_bounds__(256) void conv_silu_kernel(
    const float* __restrict__ xz, const float* __restrict__ cw,
    const float* __restrict__ cb, float* __restrict__ xb) {
  int idx = blockIdx.x * 256 + threadIdx.x;          // ROWS*DIN/4 total
  int row = idx / (DIN / 4);                         // b*L + l
  int d4 = idx - row * (DIN / 4);
  int d = d4 << 2;
  int l = row & (LL - 1);
  const float* col = xz + (size_t)row * (2 * DIN) + d;
  float4 x0 = *(const float4*)col;
  float4 x1 = make_float4(0, 0, 0, 0), x2 = x1, x3 = x1;
  if (l >= 1) x1 = *(const float4*)(col - 2 * DIN);
  if (l >= 2) x2 = *(const float4*)(col - 4 * DIN);
  if (l >= 3) x3 = *(const float4*)(col - 6 * DIN);
  float4 bb = *(const float4*)(cb + d);
  // cw[d][k]: k=3 is current tap, k=0 oldest
  float4 wa = *(const float4*)(cw + (size_t)(d + 0) * 4);
  float4 wb = *(const float4*)(cw + (size_t)(d + 1) * 4);
  float4 wc = *(const float4*)(cw + (size_t)(d + 2) * 4);
  float4 wd = *(const float4*)(cw + (size_t)(d + 3) * 4);
  float4 r;
  r.x = bb.x + wa.w * x0.x + wa.z * x1.x + wa.y * x2.x + wa.x * x3.x;
  r.y = bb.y + wb.w * x0.y + wb.z * x1.y + wb.y * x2.y + wb.x * x3.y;
  r.z = bb.z + wc.w * x0.z + wc.z * x1.z + wc.y * x2.z + wc.x * x3.z;
  r.w = bb.w + wd.w * x0.w + wd.z * x1.w + wd.y * x2.w + wd.x * x3.w;
  r.x = r.x / (1.0f + __expf(-r.x));
  r.y = r.y / (1.0f + __expf(-r.y));
  r.z = r.z / (1.0f + __expf(-r.z));
  r.w = r.w / (1.0f + __expf(-r.w));
  *(float4*)(xb + (size_t)row * DIN + d) = r;
}

// ---------------- fp32 GEMM (small shapes: x_proj, dt_proj) ----------------
// C(M x N) = A(M x K) * W(N x K)^T.  EPI: 0 = none, 1 = softplus(acc+bias[n])
// gridDim.z > 1 => split-K: each z-slice does K/gridDim.z and atomicAdds into
// a pre-zeroed C (EPI must be 0 in that case).
__device__ __forceinline__ float softplus_f(float t) {
  return t > 20.0f ? t : log1pf(__expf(t));
}

template <int EPI>
__global__ __launch_bounds__(256) void sgemm_nt(
    const float* __restrict__ A, int lda,
    const float* __restrict__ W, int ldw,
    float* __restrict__ C, int ldc,
    int N, int K, const float* __restrict__ bias) {
  __shared__ float As[16][68];
  __shared__ float Ws[16][68];
  const int tid = threadIdx.x;
  const int tx = tid & 15, ty = tid >> 4;
  const int bm = blockIdx.x, bn = blockIdx.y;
  const int kLen = K / gridDim.z;
  const int kBegin = blockIdx.z * kLen;
  const int kEnd = kBegin + kLen;
  const int lrow = tid >> 2;          // 0..63
  const int lk4 = (tid & 3) << 2;     // 0,4,8,12
  const float* Aptr = A + (size_t)(bm * 64 + lrow) * lda + lk4;
  const int wrow = bn * 64 + lrow;
  const float* Wptr = W + (size_t)wrow * ldw + lk4;
  const bool wvalid = wrow < N;
  float c[4][4] = {};
  for (int k0 = kBegin; k0 < kEnd; k0 += 16) {
    float4 a4 = *(const float4*)(Aptr + k0);
    float4 w4 = wvalid ? *(const float4*)(Wptr + k0) : make_float4(0, 0, 0, 0);
    __syncthreads();
    As[lk4 + 0][lrow] = a4.x; As[lk4 + 1][lrow] = a4.y;
    As[lk4 + 2][lrow] = a4.z; As[lk4 + 3][lrow] = a4.w;
    Ws[lk4 + 0][lrow] = w4.x; Ws[lk4 + 1][lrow] = w4.y;
    Ws[lk4 + 2][lrow] = w4.z; Ws[lk4 + 3][lrow] = w4.w;
    __syncthreads();
#pragma unroll
    for (int k = 0; k < 16; k++) {
      float4 a = *(const float4*)&As[k][ty << 2];
      float4 w = *(const float4*)&Ws[k][tx << 2];
      c[0][0] += a.x * w.x; c[0][1] += a.x * w.y; c[0][2] += a.x * w.z; c[0][3] += a.x * w.w;
      c[1][0] += a.y * w.x; c[1][1] += a.y * w.y; c[1][2] += a.y * w.z; c[1][3] += a.y * w.w;
      c[2][0] += a.z * w.x; c[2][1] += a.z * w.y; c[2][2] += a.z * w.z; c[2][3] += a.z * w.w;
      c[3][0] += a.w * w.x; c[3][1] += a.w * w.y; c[3][2] += a.w * w.z; c[3][3] += a.w * w.w;
    }
  }
  const int m0 = bm * 64 + (ty << 2);
  const int n0 = bn * 64 + (tx << 2);
  const bool split = gridDim.z > 1;
#pragma unroll
  for (int i = 0; i < 4; i++) {
    float* crow = C + (size_t)(m0 + i) * ldc;
#pragma unroll
    for (int j = 0; j < 4; j++) {
      int n = n0 + j;
      if (n < N) {
        float v = c[i][j];
        if constexpr (EPI == 1) v = softplus_f(v + bias[n]);
        if (split) atomicAdd(&crow[n], v);
        else crow[n] = v;
      }
    }
  }
}

// ---------------- bf16 MFMA GEMM (m97 structure, BK=64) ----------------
// C(M x N) = A(M x K)_bf16 * W(N x K)_bf16^T, fp32 out.
// 128x128 tile, BK=64 (two 32-col subtiles staged per barrier: 8 loads in
// flight/thread, half the barrier-drain events vs BK=32 — the k-steps are
// latency-bound, not BW-bound: measured 0.58 TB/s fetch at 22% MfmaUtil).
// global_load_lds 16B staging, 4 waves as 2x2 of 64x64.
// XCD-aware block swizzle (T1): blocks sharing a W-panel land on one XCD's L2.
// Requires: M,N multiples of 128; K multiple of 64; lda/ldw multiples of 8.
// EPI: 0 = none, 2 = C += acc (residual), 3 = acc + bias[n]

__device__ __forceinline__ void gload16(const void* g, void* l) {
  __builtin_amdgcn_global_load_lds(
      (const __attribute__((address_space(1))) void*)g,
      (__attribute__((address_space(3))) void*)l, 16, 0, 0);
}

template <int EPI>
__global__ __launch_bounds__(256) void bgemm_nt(
    const __hip_bfloat16* __restrict__ A, int lda,
    const __hip_bfloat16* __restrict__ W, int ldw,
    float* __restrict__ C, int ldc,
    int K, const float* __restrict__ bias) {
  __shared__ short As[2][128 * 32];   // 16 KB: two K-subtiles (cols k0, k0+32)
  __shared__ short Ws[2][128 * 32];   // 16 KB
  const int tid = threadIdx.x;
  const int wave = tid >> 6, lane = tid & 63;
  const int wm = wave >> 1, wn = wave & 1;

  // XCD swizzle: hardware assigns XCD = flat_dispatch_id % 8; remap so each
  // XCD owns a contiguous range of tiles (contiguous N-panels -> L2 reuse).
  const int nbx = gridDim.x;
  const int nwg = nbx * gridDim.y;
  int flat = blockIdx.y * nbx + blockIdx.x;
  if ((nwg & 7) == 0) {
    int chunk = nwg >> 3;
    flat = (flat & 7) * chunk + (flat >> 3);
  }
  const int tileM = (flat % nbx) * 128, tileN = (flat / nbx) * 128;

  const short* Ag = (const short*)A;
  const short* Wg = (const short*)W;
  // staging: chunk cid covers tile row cid>>2, bf16 cols [(cid&3)*8, +8)
  // within a 32-col subtile.
  const int cid0 = tid, cid1 = tid + 256;
  const size_t aOff0 = (size_t)(tileM + (cid0 >> 2)) * lda + (cid0 & 3) * 8;
  const size_t aOff1 = (size_t)(tileM + (cid1 >> 2)) * lda + (cid1 & 3) * 8;
  const size_t wOff0 = (size_t)(tileN + (cid0 >> 2)) * ldw + (cid0 & 3) * 8;
  const size_t wOff1 = (size_t)(tileN + (cid1 >> 2)) * ldw + (cid1 & 3) * 8;
  // LDS dst: wave-uniform base + lane*16B (implicit)
  const int wb0 = wave * 512, wb1 = 2048 + wave * 512;

  const int fr = lane & 15, fq = lane >> 4;
  f32x4 acc[4][4] = {};

  for (int k0 = 0; k0 < K; k0 += 64) {
    gload16(Ag + aOff0 + k0, As[0] + wb0);
    gload16(Ag + aOff1 + k0, As[0] + wb1);
    gload16(Wg + wOff0 + k0, Ws[0] + wb0);
    gload16(Wg + wOff1 + k0, Ws[0] + wb1);
    gload16(Ag + aOff0 + k0 + 32, As[1] + wb0);
    gload16(Ag + aOff1 + k0 + 32, As[1] + wb1);
    gload16(Wg + wOff0 + k0 + 32, Ws[1] + wb0);
    gload16(Wg + wOff1 + k0 + 32, Ws[1] + wb1);
    __syncthreads();                    // drains vmcnt -> LDS visible
#pragma unroll
    for (int s = 0; s < 2; s++) {
      short8 afr[4], bfr[4];
#pragma unroll
      for (int t = 0; t < 4; t++) {
        afr[t] = *(const short8*)(As[s] + (wm * 64 + t * 16 + fr) * 32 + fq * 8);
        bfr[t] = *(const short8*)(Ws[s] + (wn * 64 + t * 16 + fr) * 32 + fq * 8);
      }
#pragma unroll
      for (int mt = 0; mt < 4; mt++)
#pragma unroll
        for (int nt = 0; nt < 4; nt++)
          acc[mt][nt] = __builtin_amdgcn_mfma_f32_16x16x32_bf16(
              afr[mt], bfr[nt], acc[mt][nt], 0, 0, 0);
    }
    __syncthreads();                    // LDS reads done before next stage
  }

  // C/D layout: col = lane&15, row = (lane>>4)*4 + reg
#pragma unroll
  for (int mt = 0; mt < 4; mt++) {
#pragma unroll
    for (int r = 0; r < 4; r++) {
      int row = tileM + wm * 64 + mt * 16 + fq * 4 + r;
      float* crow = C + (size_t)row * ldc;
#pragma unroll
      for (int nt = 0; nt < 4; nt++) {
        int col = tileN + wn * 64 + nt * 16 + fr;
        float v = acc[mt][nt][r];
        if constexpr (EPI == 2) v += crow[col];
        else if constexpr (EPI == 3) v += bias[col];
        crow[col] = v;
      }
    }
  }
}

// ---------------- chunked selective scan ----------------
// h_t = exp(delta_t * A) * h_{t-1} + delta_t * B_t * u_t  is a linear
// recurrence; chunk-compose with P_chunk = exp(A * sum(delta over chunk)).
// pass1: per chunk, run from h=0 -> q_c (chunk contribution) + sum(delta).
// pass2: serial carry over NCH chunks -> entry state per chunk.
// pass3: re-run each chunk from its entry state, emit gated y (bf16).
// Layout: one channel d per lane (coalesced u/delta/z), 16 states in regs
// (16 independent FMA chains of ILP, no cross-lane ops).

__global__ __launch_bounds__(256) void scan_pass1(
    const float* __restrict__ u,      // xb   (2048 x 1536)
    const float* __restrict__ dlt,    // delta(2048 x 1536)
    const float* __restrict__ xdbl,   // (2048 x 80): B at +48
    const float* __restrict__ A_log,  // layer slice (1536 x 16)
    float* __restrict__ qbuf,         // (B, NCH, DIN, NS)
    float* __restrict__ sdel) {       // (B, NCH, DIN)
  const int d = blockIdx.x * 256 + threadIdx.x;   // 0..1535
  const int c = blockIdx.y;                       // 0..NCH-2
  const int b = blockIdx.z;
  float Ac2[NS];
  {
    const float* ar = A_log + (size_t)d * NS;
#pragma unroll
    for (int j = 0; j < NS; j++) Ac2[j] = -__expf(ar[j]) * 1.44269504f;
  }
  const int l0 = c * CLEN;
  const float* ur = u   + ((size_t)b * LL + l0) * DIN + d;
  const float* dr = dlt + ((size_t)b * LL + l0) * DIN + d;
  const float* br = xdbl + ((size_t)b * LL + l0) * 80 + DTRK;
  float h[NS];
#pragma unroll
  for (int j = 0; j < NS; j++) h[j] = 0.0f;
  float sd = 0.0f;
  for (int t = 0; t < CLEN; t++) {
    float dl = dr[(size_t)t * DIN];
    float ul = ur[(size_t)t * DIN];
    float Bv[NS];
    *(float4*)&Bv[0]  = *(const float4*)(br + (size_t)t * 80);
    *(float4*)&Bv[4]  = *(const float4*)(br + (size_t)t * 80 + 4);
    *(float4*)&Bv[8]  = *(const float4*)(br + (size_t)t * 80 + 8);
    *(float4*)&Bv[12] = *(const float4*)(br + (size_t)t * 80 + 12);
    sd += dl;
    float du = dl * ul;
#pragma unroll
    for (int j = 0; j < NS; j++)
      h[j] = exp2f(dl * Ac2[j]) * h[j] + du * Bv[j];
  }
  float* qo = qbuf + (((size_t)b * NCH + c) * DIN + d) * NS;
#pragma unroll
  for (int j = 0; j < NS; j += 4)
    *(float4*)(qo + j) = make_float4(h[j], h[j + 1], h[j + 2], h[j + 3]);
  sdel[((size_t)b * NCH + c) * DIN + d] = sd;
}

__global__ __launch_bounds__(256) void scan_pass2(
    const float* __restrict__ qbuf, const float* __restrict__ sdel,
    const float* __restrict__ A_log, float* __restrict__ hstart) {
  const int e = blockIdx.x * 256 + threadIdx.x;   // over DIN*NS = 24576
  const int n = e & (NS - 1);
  const int d = e >> 4;
  const int b = blockIdx.y;
  float Ac2 = -__expf(A_log[(size_t)d * NS + n]) * 1.44269504f;
  float h = 0.0f;
  for (int c = 0; c < NCH; c++) {
    hstart[(((size_t)b * NCH + c) * DIN + d) * NS + n] = h;   // state BEFORE chunk c
    if (c + 1 < NCH) {
      float sd = sdel[((size_t)b * NCH + c) * DIN + d];
      float q  = qbuf[(((size_t)b * NCH + c) * DIN + d) * NS + n];
      h = exp2f(Ac2 * sd) * h + q;
    }
  }
}

__global__ __launch_bounds__(256) void scan_pass3(
    const float* __restrict__ u,      // xb
    const float* __restrict__ dlt,    // delta
    const float* __restrict__ xdbl,   // B at +48, C at +64
    const float* __restrict__ xz,     // z at col DIN+d, stride 2*DIN
    const float* __restrict__ A_log,  // layer slice (1536 x 16)
    const float* __restrict__ Dv,     // layer slice (1536)
    const float* __restrict__ hstart, // (B, NCH, DIN, NS)
    __hip_bfloat16* __restrict__ y) { // (2048 x 1536) bf16
  const int d = blockIdx.x * 256 + threadIdx.x;
  const int c = blockIdx.y;
  const int b = blockIdx.z;
  float Ac2[NS];
  {
    const float* ar = A_log + (size_t)d * NS;
#pragma unroll
    for (int j = 0; j < NS; j++) Ac2[j] = -__expf(ar[j]) * 1.44269504f;
  }
  const float Dd = Dv[d];
  float h[NS];
  {
    const float* hs = hstart + (((size_t)b * NCH + c) * DIN + d) * NS;
#pragma unroll
    for (int j = 0; j < NS; j += 4) {
      float4 hv = *(const float4*)(hs + j);
      h[j] = hv.x; h[j + 1] = hv.y; h[j + 2] = hv.z; h[j + 3] = hv.w;
    }
  }
  const int l0 = c * CLEN;
  const float* ur = u   + ((size_t)b * LL + l0) * DIN + d;
  const float* dr = dlt + ((size_t)b * LL + l0) * DIN + d;
  const float* br = xdbl + ((size_t)b * LL + l0) * 80 + DTRK;      // B
  const float* cr = br + NS;                                       // C
  const float* zr = xz + ((size_t)b * LL + l0) * (2 * DIN) + DIN + d;
  __hip_bfloat16* yr = y + ((size_t)b * LL + l0) * DIN + d;
  for (int t = 0; t < CLEN; t++) {
    float dl = dr[(size_t)t * DIN];
    float ul = ur[(size_t)t * DIN];
    float zl = zr[(size_t)t * (2 * DIN)];
    float Bv[NS], Cv[NS];
    *(float4*)&Bv[0]  = *(const float4*)(br + (size_t)t * 80);
    *(float4*)&Bv[4]  = *(const float4*)(br + (size_t)t * 80 + 4);
    *(float4*)&Bv[8]  = *(const float4*)(br + (size_t)t * 80 + 8);
    *(float4*)&Bv[12] = *(const float4*)(br + (size_t)t * 80 + 12);
    *(float4*)&Cv[0]  = *(const float4*)(cr + (size_t)t * 80);
    *(float4*)&Cv[4]  = *(const float4*)(cr + (size_t)t * 80 + 4);
    *(float4*)&Cv[8]  = *(const float4*)(cr + (size_t)t * 80 + 8);
    *(float4*)&Cv[12] = *(const float4*)(cr + (size_t)t * 80 + 12);
    float du = dl * ul;
    float acc = 0.0f;
#pragma unroll
    for (int j = 0; j < NS; j++) {
      h[j] = exp2f(dl * Ac2[j]) * h[j] + du * Bv[j];
      acc += h[j] * Cv[j];
    }
    acc += ul * Dd;
    float sig = 1.0f / (1.0f + __expf(-zl));
    yr[(size_t)t * DIN] = __float2bfloat16(acc * (zl * sig));
  }
}

// ---------------- launch ----------------

extern "C" void kernel_launch(void* const* d_in, const int* in_sizes, int n_in,
                              void* d_out, int out_size, void* d_ws,
                              size_t ws_size, hipStream_t stream) {
  const int*   tokens    = (const int*)d_in[0];
  const float* embedding = (const float*)d_in[1];
  const float* W_out_w   = (const float*)d_in[2];
  const float* W_out_b   = (const float*)d_in[3];
  const float* norm_w    = (const float*)d_in[4];
  const float* in_proj_w = (const float*)d_in[5];
  const float* conv_w    = (const float*)d_in[6];
  const float* conv_b    = (const float*)d_in[7];
  const float* x_proj_w  = (const float*)d_in[8];
  const float* dt_proj_w = (const float*)d_in[9];
  const float* dt_proj_b = (const float*)d_in[10];
  const float* A_log     = (const float*)d_in[11];
  const float* Dvec      = (const float*)d_in[12];
  const float* out_proj_w= (const float*)d_in[13];
  float* out = (float*)d_out;

  float* ws = (float*)d_ws;
  float* x    = ws;                          // 2048*768
  float* xz   = x + (size_t)ROWS * DD;       // 2048*3072
  float* xb   = xz + (size_t)ROWS * 2 * DIN; // 2048*1536
  float* xdbl = xb + (size_t)ROWS * DIN;     // 2048*80
  float* dlt  = xdbl + (size_t)ROWS * 80;    // 2048*1536
  __hip_bfloat16* bfbase = (__hip_bfloat16*)(dlt + (size_t)ROWS * DIN);
  __hip_bfloat16* xnb  = bfbase;                         // 2048*768
  __hip_bfloat16* ybb  = xnb + (size_t)ROWS * DD;        // 2048*1536
  __hip_bfloat16* xbf  = ybb + (size_t)ROWS * DIN;       // 2048*768
  __hip_bfloat16* wInB = xbf + (size_t)ROWS * DD;        // 4*3072*768
  __hip_bfloat16* wOpB = wInB + (size_t)NLAY * 2 * DIN * DD; // 4*768*1536
  __hip_bfloat16* wLgB = wOpB + (size_t)NLAY * DD * DIN; // 32000*768
  // chunked-scan carry buffers (fp32), after the bf16 region
  float* qbuf   = (float*)(wLgB + (size_t)VV * DD);      // B*NCH*DIN*NS
  float* sdel   = qbuf + (size_t)BB * NCH * DIN * NS;    // B*NCH*DIN
  float* hstart = sdel + (size_t)BB * NCH * DIN;         // B*NCH*DIN*NS

  // weight conversions (every call; same work each call) -- one launch
  cvt3_bf16_kernel<<<2048, 256, 0, stream>>>(
      in_proj_w, wInB, NLAY * 2 * DIN * DD / 4,
      out_proj_w, wOpB, NLAY * DD * DIN / 4,
      W_out_w, wLgB, VV * DD / 4);

  embed_kernel<<<ROWS * DD / 256, 256, 0, stream>>>(tokens, embedding, x);

  for (int i = 0; i < NLAY; i++) {
    rmsnorm_kernel<<<ROWS, 256, 0, stream>>>(x, norm_w + (size_t)i * DD, xnb);
    // xz = xn @ in_proj^T   (2048x768)x(3072x768)^T  [bf16 MFMA]
    bgemm_nt<0><<<dim3(16, 24), 256, 0, stream>>>(
        xnb, DD, wInB + (size_t)i * 2 * DIN * DD, DD, xz, 2 * DIN, DD,
        nullptr);
    // xb = silu(conv(xz[:, :DIN]))
    conv_silu_kernel<<<ROWS * DIN / 4 / 256, 256, 0, stream>>>(
        xz, conv_w + (size_t)i * DIN * DCV, conv_b + (size_t)i * DIN, xb);
    // x_dbl = xb @ x_proj^T (2048x1536)x(80x1536)^T  [fp32, split-K x8]
    zero_kernel<<<ROWS * 80 / 256, 256, 0, stream>>>(xdbl, ROWS * 80);
    sgemm_nt<0><<<dim3(32, 2, 8), 256, 0, stream>>>(
        xb, DIN, x_proj_w + (size_t)i * (DTRK + 2 * NS) * DIN, DIN, xdbl,
        DTRK + 2 * NS, DTRK + 2 * NS, DIN, nullptr);
    // delta = softplus(dt @ dt_proj^T + dt_b) (2048x48)x(1536x48)^T [fp32]
    sgemm_nt<1><<<dim3(32, 24), 256, 0, stream>>>(
        xdbl, DTRK + 2 * NS, dt_proj_w + (size_t)i * DIN * DTRK, DTRK, dlt,
        DIN, DIN, DTRK, dt_proj_b + (size_t)i * DIN);
    // selective scan + gating -> ybb (bf16), chunked 3-pass
    const float* Ai = A_log + (size_t)i * DIN * NS;
    scan_pass1<<<dim3(DIN / 256, NCH - 1, BB), 256, 0, stream>>>(
        xb, dlt, xdbl, Ai, qbuf, sdel);
    scan_pass2<<<dim3(DIN * NS / 256, BB), 256, 0, stream>>>(
        qbuf, sdel, Ai, hstart);
    scan_pass3<<<dim3(DIN / 256, NCH, BB), 256, 0, stream>>>(
        xb, dlt, xdbl, xz, Ai, Dvec + (size_t)i * DIN, hstart, ybb);
    // x += yb @ out_proj^T  (2048x1536)x(768x1536)^T  [bf16 MFMA]
    bgemm_nt<2><<<dim3(16, 6), 256, 0, stream>>>(
        ybb, DIN, wOpB + (size_t)i * DD * DIN, DIN, x, DD, DIN, nullptr);
  }

  // logits = x @ W_out^T + b  (2048x768)x(32000x768)^T  [bf16 MFMA]
  {
    int n4 = ROWS * DD / 4;
    cvt_bf16_kernel<<<(n4 + 255) / 256, 256, 0, stream>>>(x, xbf, n4);
  }
  bgemm_nt<3><<<dim3(16, 250), 256, 0, stream>>>(
      xbf, DD, wLgB, DD, out, VV, DD, W_out_b);
}